// Round 1
// 822.302 us; speedup vs baseline: 1.4085x; 1.4085x over previous
//
#include <hip/hip_runtime.h>
#include <hip/hip_bf16.h>

// MoE forward, MI355X. B=4,S=2048,H=1024,E=8,F=4096,K=2.
// router (no atomics) -> slots (single-block scan: counts, 128-aligned offsets,
// deterministic slot assignment) -> gather x->bf16 -> grouped bf16 MFMA GEMM1
// (+gelu) -> grouped GEMM2 (+b2) -> combine (p0*(y1+y2)).
// GEMM K-loop: BK=32 ping-pong double-buffer in 32 KB LDS; global-side XOR
// swizzle keeps ds_read_b128 conflict-free. MFMA operands SWAPPED
// (mfma(b,a,acc)) so each lane's 4 acc regs span 4 consecutive N columns:
// epilogue = bf16x4 stores + float4 bias loads + sigmoid-form gelu.
// Workspace (bytes), total ~313 MB:
//   [0,36) off[9]
//   [256,..) e01[8192] | [33024,..) p0[8192] | [65792,..) slot1 | [98560,..) slot2
//   [131584,..)   Xg bf16 [17408][1024] (reused as ybuf)
//   [35783168,..) W1t bf16 [8][4096][1024]
//   [102892032,..)W2t bf16 [8][1024][4096]
//   [170000896,..)h  bf16 [17408][4096]  (ends 312607232)

typedef __bf16 bf16;
typedef __attribute__((ext_vector_type(4))) __bf16 bf16x4;
typedef __attribute__((ext_vector_type(8))) __bf16 bf16x8;
typedef __attribute__((ext_vector_type(4))) float f32x4;

#define GLD16(g, l) __builtin_amdgcn_global_load_lds( \
    (__attribute__((address_space(1))) void*)(g),      \
    (__attribute__((address_space(3))) void*)(l), 16, 0, 0)

// gelu tanh-approx == v * sigmoid(2c), 2c = 1.5957691216*v + 0.07135481627*v^3.
__device__ __forceinline__ float gelu_fast(float v) {
  float u = v * fmaf(v * v, 0.0713548162726f, 1.5957691216057308f);
  return v * __builtin_amdgcn_rcpf(1.0f + __expf(-u));
}

// ---------------- router: 1 wave per token, no atomics ----------------
__global__ __launch_bounds__(256) void router_kernel(
    const float* __restrict__ x, const float* __restrict__ Wr,
    const float* __restrict__ br, int* __restrict__ e01,
    float* __restrict__ p0arr) {
  int wv = threadIdx.x >> 6;
  int l = threadIdx.x & 63;
  int t = blockIdx.x * 4 + wv;
  float acc[8];
#pragma unroll
  for (int e = 0; e < 8; e++) acc[e] = 0.f;
  const float* xr = x + (size_t)t * 1024;
#pragma unroll
  for (int i = 0; i < 16; i++) {
    int h = l + i * 64;
    float xv = xr[h];
    const float4* w4 = (const float4*)(Wr + h * 8);
    float4 wa = w4[0], wb = w4[1];
    acc[0] += xv * wa.x; acc[1] += xv * wa.y; acc[2] += xv * wa.z; acc[3] += xv * wa.w;
    acc[4] += xv * wb.x; acc[5] += xv * wb.y; acc[6] += xv * wb.z; acc[7] += xv * wb.w;
  }
#pragma unroll
  for (int e = 0; e < 8; e++) {
    float v = acc[e];
#pragma unroll
    for (int m = 1; m < 64; m <<= 1) v += __shfl_xor(v, m, 64);
    acc[e] = v + br[e];
  }
  int i1 = 0; float m1 = acc[0];
#pragma unroll
  for (int e = 1; e < 8; e++) { if (acc[e] > m1) { m1 = acc[e]; i1 = e; } }
  int i2 = -1; float m2 = -3.4e38f;
#pragma unroll
  for (int e = 0; e < 8; e++) { if (e != i1 && acc[e] > m2) { m2 = acc[e]; i2 = e; } }
  if (l == 0) {
    e01[t] = i1 | (i2 << 8);
    p0arr[t] = 1.0f / (1.0f + __expf(m2 - m1));  // normalized top-1 prob
  }
}

// ---------------- slots: counts + offsets + slot assignment, no atomics -----
// One block, 1024 threads, 8 tokens/thread. Per expert: thread-local count ->
// wave shfl_up scan -> per-wave totals in LDS -> block exclusive base ->
// deterministic slot = off[e] + rank (token order).
__global__ __launch_bounds__(1024) void slots_kernel(
    const int* __restrict__ e01, int* __restrict__ off,
    int* __restrict__ slot1, int* __restrict__ slot2) {
  __shared__ int wtot[16];
  int tid = threadIdx.x;
  int l = tid & 63, wv = tid >> 6;
  int t0 = tid * 8;
  int i1[8], i2[8];
#pragma unroll
  for (int i = 0; i < 8; i++) {
    int ee = e01[t0 + i];
    i1[i] = ee & 255;
    i2[i] = (ee >> 8) & 255;
  }
  int running = 0;  // padded cumulative offset (identical in all threads)
  for (int e = 0; e < 8; e++) {
    int cthread = 0;
#pragma unroll
    for (int i = 0; i < 8; i++) cthread += (i1[i] == e) + (i2[i] == e);
    int inc = cthread;
#pragma unroll
    for (int d = 1; d < 64; d <<= 1) {
      int v = __shfl_up(inc, d, 64);
      if (l >= d) inc += v;
    }
    if (l == 63) wtot[wv] = inc;
    __syncthreads();
    int wbase = 0, total = 0;
#pragma unroll
    for (int w = 0; w < 16; w++) {
      int tw = wtot[w];
      wbase += (w < wv) ? tw : 0;
      total += tw;
    }
    int base = running + wbase + (inc - cthread);
#pragma unroll
    for (int i = 0; i < 8; i++) {
      if (i1[i] == e) { slot1[t0 + i] = base; base++; }
      if (i2[i] == e) { slot2[t0 + i] = base; base++; }
    }
    if (tid == 0) off[e] = running;
    running += (total + 127) & ~127;
    __syncthreads();  // protect wtot for next pass
  }
  if (tid == 0) off[8] = running;
}

// ---------------- gather: x -> bf16 into both expert slots ----------------
__global__ __launch_bounds__(256) void gather_kernel(
    const float* __restrict__ x, const int* __restrict__ slot1,
    const int* __restrict__ slot2, bf16* __restrict__ Xg) {
  int t = blockIdx.x;
  int s1 = slot1[t], s2 = slot2[t];
  float4 v = ((const float4*)(x + (size_t)t * 1024))[threadIdx.x];
  bf16x4 bv = { (bf16)v.x, (bf16)v.y, (bf16)v.z, (bf16)v.w };
  *(bf16x4*)(Xg + (size_t)s1 * 1024 + threadIdx.x * 4) = bv;
  *(bf16x4*)(Xg + (size_t)s2 * 1024 + threadIdx.x * 4) = bv;
}

// ---------------- transpose + fp32->bf16: in [E][R][C] -> out [E][C][R] ----
__global__ __launch_bounds__(256) void tconv_kernel(
    const float* __restrict__ in, bf16* __restrict__ out, int R, int C) {
  __shared__ float tile[64][65];
  size_t base = (size_t)blockIdx.z * R * C;
  int gr0 = blockIdx.y * 64, gc0 = blockIdx.x * 64;
#pragma unroll
  for (int i = 0; i < 16; i++) {
    int idx = threadIdx.x + i * 256;
    int r = idx >> 6, c = idx & 63;
    tile[r][c] = in[base + (size_t)(gr0 + r) * C + gc0 + c];
  }
  __syncthreads();
  int rr0 = (threadIdx.x & 15) * 4;
#pragma unroll
  for (int i = 0; i < 4; i++) {
    int cc = (threadIdx.x >> 4) + i * 16;
    bf16x4 v = { (bf16)tile[rr0][cc], (bf16)tile[rr0 + 1][cc],
                 (bf16)tile[rr0 + 2][cc], (bf16)tile[rr0 + 3][cc] };
    *(bf16x4*)&out[base + (size_t)(gc0 + cc) * R + gr0 + rr0] = v;
  }
}

// ======================= GEMM core (BK=32, ping-pong) ========================
// A [M][K], B[N][K], both bf16 K-contig. 128x128 block tile, 4 waves, each
// 64x64 (4x4 of 16x16x32 MFMA). Staging: global-side XOR swizzle cg^=(row&3);
// LDS dest is lane-contiguous (global_load_lds constraint).
// MFMA called as mfma(bfr, af, acc): C/D row index -> N, col index -> M, so
// lane l holds C[m = mt*16 + (l&15)][n = nt*16 + (l>>4)*4 + jj] -> per-lane
// 4 consecutive columns => vectorized bf16x4 epilogue stores.
struct GemmCtx {
  const bf16* Abase;
  const bf16* Bbase;
  int K;
  int w, l, mbase, nbase;
};

__device__ __forceinline__ void gemm_mainloop(
    const GemmCtx& c, bf16* As0, bf16* As1, bf16* Bs0, bf16* Bs1,
    f32x4 acc[4][4]) {
  const int K = c.K;
  const int NT = K >> 5;
  int w = c.w, l = c.l;
  int gr = w * 32 + (l >> 2);          // this lane's first staged row (of 2)
  int cg = (l & 3) ^ ((l >> 2) & 3);   // global colgroup (XOR swizzle)
  const bf16* Ap = c.Abase + (size_t)gr * K + cg * 8;
  const bf16* Bp = c.Bbase + (size_t)gr * K + cg * 8;
  int ldsoff = w * 1024 + l * 8;       // elements; +512 for second 16-row seg
  // prologue: stage kt=0 into buf0
  {
    GLD16(Ap, As0 + ldsoff);
    GLD16(Ap + (size_t)16 * K, As0 + ldsoff + 512);
    GLD16(Bp, Bs0 + ldsoff);
    GLD16(Bp + (size_t)16 * K, Bs0 + ldsoff + 512);
  }
  int arow[4], brow[4];
#pragma unroll
  for (int t = 0; t < 4; t++) {
    arow[t] = c.mbase + t * 16 + (l & 15);
    brow[t] = c.nbase + t * 16 + (l & 15);
  }
  int kc = l >> 4;  // global colgroup wanted by this lane's fragment
  for (int kt = 0; kt < NT; kt++) {
    __syncthreads();  // vmcnt(0): buf[kt&1] loads (issued last iter) landed
    bf16* Ab = (kt & 1) ? As1 : As0;
    bf16* Bb = (kt & 1) ? Bs1 : Bs0;
    if (kt + 1 < NT) {
      bf16* An = (kt & 1) ? As0 : As1;
      bf16* Bn = (kt & 1) ? Bs0 : Bs1;
      const bf16* Ag = Ap + (size_t)(kt + 1) * 32;
      const bf16* Bg = Bp + (size_t)(kt + 1) * 32;
      GLD16(Ag, An + ldsoff);
      GLD16(Ag + (size_t)16 * K, An + ldsoff + 512);
      GLD16(Bg, Bn + ldsoff);
      GLD16(Bg + (size_t)16 * K, Bn + ldsoff + 512);
    }
    bf16x8 af[4], bfr[4];
#pragma unroll
    for (int t = 0; t < 4; t++) {
      int cgl = kc ^ (arow[t] & 3);
      af[t] = *(const bf16x8*)&Ab[arow[t] * 32 + cgl * 8];
    }
#pragma unroll
    for (int t = 0; t < 4; t++) {
      int cgl = kc ^ (brow[t] & 3);
      bfr[t] = *(const bf16x8*)&Bb[brow[t] * 32 + cgl * 8];
    }
#pragma unroll
    for (int mt = 0; mt < 4; mt++)
#pragma unroll
      for (int nt = 0; nt < 4; nt++)
        acc[mt][nt] = __builtin_amdgcn_mfma_f32_16x16x32_bf16(bfr[nt], af[mt], acc[mt][nt], 0, 0, 0);
  }
}

// ---------------- grouped GEMM1: h = gelu(Xg @ W1[e] + b1[e]) ----------------
// Flat grid 4352: xcd=b&7, j=b>>3; m_tile=xcd*17+j/32, n_tile=j%32.
__global__ __launch_bounds__(256) void gemm1_kernel(
    const bf16* __restrict__ Xg, const bf16* __restrict__ W1t,
    const float* __restrict__ b1, bf16* __restrict__ hbuf,
    const int* __restrict__ off) {
  __shared__ bf16 As0[128 * 32], As1[128 * 32];
  __shared__ bf16 Bs0[128 * 32], Bs1[128 * 32];
  const int K = 1024;
  int b = blockIdx.x;
  int xcd = b & 7, j = b >> 3;
  int m_tile = xcd * 17 + (j >> 5);
  int n_tile = j & 31;
  int row0 = m_tile * 128;
  if (row0 >= off[8]) return;
  int e = 0;
#pragma unroll
  for (int i = 0; i < 8; i++) { if (row0 >= off[i + 1]) e = i + 1; }
  int tid = threadIdx.x;
  GemmCtx c;
  c.w = tid >> 6; c.l = tid & 63;
  c.mbase = (c.w >> 1) * 64; c.nbase = (c.w & 1) * 64;
  c.K = K;
  c.Abase = Xg + (size_t)row0 * K;
  c.Bbase = W1t + ((size_t)e * 4096 + n_tile * 128) * K;
  f32x4 acc[4][4];
#pragma unroll
  for (int a = 0; a < 4; a++)
#pragma unroll
    for (int bb = 0; bb < 4; bb++) acc[a][bb] = (f32x4){0.f, 0.f, 0.f, 0.f};
  gemm_mainloop(c, As0, As1, Bs0, Bs1, acc);
  int l = c.l;
  int mrow = l & 15, nq = (l >> 4) * 4;
  int gn0 = n_tile * 128 + c.nbase + nq;
  f32x4 bv[4];
#pragma unroll
  for (int nt = 0; nt < 4; nt++)
    bv[nt] = *(const f32x4*)(b1 + e * 4096 + gn0 + nt * 16);
#pragma unroll
  for (int mt = 0; mt < 4; mt++) {
    int gm = row0 + c.mbase + mt * 16 + mrow;
    bf16* rp = hbuf + (size_t)gm * 4096 + gn0;
#pragma unroll
    for (int nt = 0; nt < 4; nt++) {
      bf16x4 o;
#pragma unroll
      for (int jj = 0; jj < 4; jj++)
        o[jj] = (bf16)gelu_fast(acc[mt][nt][jj] + bv[nt][jj]);
      *(bf16x4*)(rp + nt * 16) = o;
    }
  }
}

// ---------------- grouped GEMM2: y[slot] = h @ W2[e] + b2[e] (bf16) ---------
// Flat grid 1088: xcd=b&7, j=b>>3; m_tile=xcd*17+j/8, n_tile=j&7.
__global__ __launch_bounds__(256) void gemm2_kernel(
    const bf16* __restrict__ hbuf, const bf16* __restrict__ W2t,
    const float* __restrict__ b2, bf16* __restrict__ yb,
    const int* __restrict__ off) {
  __shared__ bf16 As0[128 * 32], As1[128 * 32];
  __shared__ bf16 Bs0[128 * 32], Bs1[128 * 32];
  const int K = 4096;
  int b = blockIdx.x;
  int xcd = b & 7, j = b >> 3;
  int m_tile = xcd * 17 + (j >> 3);
  int n_tile = j & 7;
  int row0 = m_tile * 128;
  if (row0 >= off[8]) return;
  int e = 0;
#pragma unroll
  for (int i = 0; i < 8; i++) { if (row0 >= off[i + 1]) e = i + 1; }
  int tid = threadIdx.x;
  GemmCtx c;
  c.w = tid >> 6; c.l = tid & 63;
  c.mbase = (c.w >> 1) * 64; c.nbase = (c.w & 1) * 64;
  c.K = K;
  c.Abase = hbuf + (size_t)row0 * K;
  c.Bbase = W2t + ((size_t)e * 1024 + n_tile * 128) * K;
  f32x4 acc[4][4];
#pragma unroll
  for (int a = 0; a < 4; a++)
#pragma unroll
    for (int bb = 0; bb < 4; bb++) acc[a][bb] = (f32x4){0.f, 0.f, 0.f, 0.f};
  gemm_mainloop(c, As0, As1, Bs0, Bs1, acc);
  int l = c.l;
  int mrow = l & 15, nq = (l >> 4) * 4;
  int gn0 = n_tile * 128 + c.nbase + nq;
  f32x4 bv[4];
#pragma unroll
  for (int nt = 0; nt < 4; nt++)
    bv[nt] = *(const f32x4*)(b2 + e * 1024 + gn0 + nt * 16);
#pragma unroll
  for (int mt = 0; mt < 4; mt++) {
    int gm = row0 + c.mbase + mt * 16 + mrow;
    bf16* rp = yb + (size_t)gm * 1024 + gn0;
#pragma unroll
    for (int nt = 0; nt < 4; nt++) {
      bf16x4 o;
#pragma unroll
      for (int jj = 0; jj < 4; jj++)
        o[jj] = (bf16)(acc[mt][nt][jj] + bv[nt][jj]);
      *(bf16x4*)(rp + nt * 16) = o;
    }
  }
}

// ---------------- combine: out[t] = p0[t] * (y[s1] + y[s2]) -----------------
__global__ __launch_bounds__(256) void combine_kernel(
    const bf16* __restrict__ yb, const int* __restrict__ slot1,
    const int* __restrict__ slot2, const float* __restrict__ p0arr,
    float* __restrict__ out) {
  int t = blockIdx.x;
  int s1 = slot1[t], s2 = slot2[t];
  float w0 = p0arr[t];
  bf16x4 a = *(const bf16x4*)(yb + (size_t)s1 * 1024 + threadIdx.x * 4);
  bf16x4 b = *(const bf16x4*)(yb + (size_t)s2 * 1024 + threadIdx.x * 4);
  float4 o;
  o.x = w0 * ((float)a[0] + (float)b[0]);
  o.y = w0 * ((float)a[1] + (float)b[1]);
  o.z = w0 * ((float)a[2] + (float)b[2]);
  o.w = w0 * ((float)a[3] + (float)b[3]);
  *(float4*)(out + (size_t)t * 1024 + threadIdx.x * 4) = o;
}

extern "C" void kernel_launch(void* const* d_in, const int* in_sizes, int n_in,
                              void* d_out, int out_size, void* d_ws, size_t ws_size,
                              hipStream_t stream) {
  const float* x  = (const float*)d_in[0];
  const float* Wr = (const float*)d_in[1];
  const float* br = (const float*)d_in[2];
  const float* W1 = (const float*)d_in[3];
  const float* b1 = (const float*)d_in[4];
  const float* W2 = (const float*)d_in[5];
  const float* b2 = (const float*)d_in[6];
  float* out = (float*)d_out;

  char* ws = (char*)d_ws;
  int*   off   = (int*)(ws + 0);
  int*   e01   = (int*)(ws + 256);
  float* p0    = (float*)(ws + 33024);
  int*   slot1 = (int*)(ws + 65792);
  int*   slot2 = (int*)(ws + 98560);
  bf16*  Xg    = (bf16*)(ws + 131584);          // reused as ybuf after gemm1
  bf16*  W1t   = (bf16*)(ws + 35783168ULL);
  bf16*  W2t   = (bf16*)(ws + 102892032ULL);
  bf16*  hb    = (bf16*)(ws + 170000896ULL);
  bf16*  yb    = Xg;

  tconv_kernel<<<dim3(64, 16, 8), 256, 0, stream>>>(W1, W1t, 1024, 4096);
  tconv_kernel<<<dim3(16, 64, 8), 256, 0, stream>>>(W2, W2t, 4096, 1024);
  router_kernel<<<2048, 256, 0, stream>>>(x, Wr, br, e01, p0);
  slots_kernel<<<1, 1024, 0, stream>>>(e01, off, slot1, slot2);
  gather_kernel<<<8192, 256, 0, stream>>>(x, slot1, slot2, Xg);
  gemm1_kernel<<<4352, 256, 0, stream>>>(Xg, W1t, b1, hb, off);
  gemm2_kernel<<<1088, 256, 0, stream>>>(hb, W2t, b2, yb, off);
  combine_kernel<<<8192, 256, 0, stream>>>(yb, slot1, slot2, p0, out);
}

// Round 2
// 758.240 us; speedup vs baseline: 1.5275x; 1.0845x over previous
//
#include <hip/hip_runtime.h>
#include <hip/hip_bf16.h>

// MoE forward, MI355X. B=4,S=2048,H=1024,E=8,F=4096,K=2.
// router (no atomics) -> slots (single-block scan) -> gather x->bf16 ->
// grouped 8-phase MFMA GEMM1 (+gelu) -> grouped 8-phase GEMM2 (+b2) ->
// combine (p0*(y1+y2)).
// GEMM core: BM=128,BN=256,BK=64; 512 thr = 8 waves (2x4), wave=64x64.
// 3-buffer LDS (144KB), staged 2 K-tiles ahead via global_load_lds w/
// inverse-swizzled global source; steady-state s_waitcnt vmcnt(6) (never 0),
// raw s_barrier (no compiler vmcnt(0) drain), setprio(1) around MFMA cluster.
// LDS rows 128B, XOR swizzle byte^=(row&7)<<4 -> ds_read_b128 conflict-free.
// Workspace (bytes), total ~313 MB:
//   [0,36) off[9]
//   [256,..) e01[8192] | [33024,..) p0[8192] | [65792,..) slot1 | [98560,..) slot2
//   [131584,..)   Xg bf16 [17408][1024] (reused as ybuf)
//   [35783168,..) W1t bf16 [8][4096][1024]
//   [102892032,..)W2t bf16 [8][1024][4096]
//   [170000896,..)h  bf16 [17408][4096]  (ends 312607232)

typedef __bf16 bf16;
typedef __attribute__((ext_vector_type(4))) __bf16 bf16x4;
typedef __attribute__((ext_vector_type(8))) __bf16 bf16x8;
typedef __attribute__((ext_vector_type(4))) float f32x4;

#define GLD16(g, l) __builtin_amdgcn_global_load_lds( \
    (__attribute__((address_space(1))) void*)(g),      \
    (__attribute__((address_space(3))) void*)(l), 16, 0, 0)

// gelu tanh-approx == v * sigmoid(2c), 2c = 1.5957691216*v + 0.07135481627*v^3.
__device__ __forceinline__ float gelu_fast(float v) {
  float u = v * fmaf(v * v, 0.0713548162726f, 1.5957691216057308f);
  return v * __builtin_amdgcn_rcpf(1.0f + __expf(-u));
}

// ---------------- router: 1 wave per token, no atomics ----------------
__global__ __launch_bounds__(256) void router_kernel(
    const float* __restrict__ x, const float* __restrict__ Wr,
    const float* __restrict__ br, int* __restrict__ e01,
    float* __restrict__ p0arr) {
  int wv = threadIdx.x >> 6;
  int l = threadIdx.x & 63;
  int t = blockIdx.x * 4 + wv;
  float acc[8];
#pragma unroll
  for (int e = 0; e < 8; e++) acc[e] = 0.f;
  const float* xr = x + (size_t)t * 1024;
#pragma unroll
  for (int i = 0; i < 16; i++) {
    int h = l + i * 64;
    float xv = xr[h];
    const float4* w4 = (const float4*)(Wr + h * 8);
    float4 wa = w4[0], wb = w4[1];
    acc[0] += xv * wa.x; acc[1] += xv * wa.y; acc[2] += xv * wa.z; acc[3] += xv * wa.w;
    acc[4] += xv * wb.x; acc[5] += xv * wb.y; acc[6] += xv * wb.z; acc[7] += xv * wb.w;
  }
#pragma unroll
  for (int e = 0; e < 8; e++) {
    float v = acc[e];
#pragma unroll
    for (int m = 1; m < 64; m <<= 1) v += __shfl_xor(v, m, 64);
    acc[e] = v + br[e];
  }
  int i1 = 0; float m1 = acc[0];
#pragma unroll
  for (int e = 1; e < 8; e++) { if (acc[e] > m1) { m1 = acc[e]; i1 = e; } }
  int i2 = -1; float m2 = -3.4e38f;
#pragma unroll
  for (int e = 0; e < 8; e++) { if (e != i1 && acc[e] > m2) { m2 = acc[e]; i2 = e; } }
  if (l == 0) {
    e01[t] = i1 | (i2 << 8);
    p0arr[t] = 1.0f / (1.0f + __expf(m2 - m1));  // normalized top-1 prob
  }
}

// ---------------- slots: counts + offsets + slot assignment, no atomics -----
__global__ __launch_bounds__(1024) void slots_kernel(
    const int* __restrict__ e01, int* __restrict__ off,
    int* __restrict__ slot1, int* __restrict__ slot2) {
  __shared__ int wtot[16];
  int tid = threadIdx.x;
  int l = tid & 63, wv = tid >> 6;
  int t0 = tid * 8;
  int i1[8], i2[8];
#pragma unroll
  for (int i = 0; i < 8; i++) {
    int ee = e01[t0 + i];
    i1[i] = ee & 255;
    i2[i] = (ee >> 8) & 255;
  }
  int running = 0;  // padded cumulative offset (identical in all threads)
  for (int e = 0; e < 8; e++) {
    int cthread = 0;
#pragma unroll
    for (int i = 0; i < 8; i++) cthread += (i1[i] == e) + (i2[i] == e);
    int inc = cthread;
#pragma unroll
    for (int d = 1; d < 64; d <<= 1) {
      int v = __shfl_up(inc, d, 64);
      if (l >= d) inc += v;
    }
    if (l == 63) wtot[wv] = inc;
    __syncthreads();
    int wbase = 0, total = 0;
#pragma unroll
    for (int w = 0; w < 16; w++) {
      int tw = wtot[w];
      wbase += (w < wv) ? tw : 0;
      total += tw;
    }
    int base = running + wbase + (inc - cthread);
#pragma unroll
    for (int i = 0; i < 8; i++) {
      if (i1[i] == e) { slot1[t0 + i] = base; base++; }
      if (i2[i] == e) { slot2[t0 + i] = base; base++; }
    }
    if (tid == 0) off[e] = running;
    running += (total + 127) & ~127;
    __syncthreads();  // protect wtot for next pass
  }
  if (tid == 0) off[8] = running;
}

// ---------------- gather: x -> bf16 into both expert slots ----------------
__global__ __launch_bounds__(256) void gather_kernel(
    const float* __restrict__ x, const int* __restrict__ slot1,
    const int* __restrict__ slot2, bf16* __restrict__ Xg) {
  int t = blockIdx.x;
  int s1 = slot1[t], s2 = slot2[t];
  float4 v = ((const float4*)(x + (size_t)t * 1024))[threadIdx.x];
  bf16x4 bv = { (bf16)v.x, (bf16)v.y, (bf16)v.z, (bf16)v.w };
  *(bf16x4*)(Xg + (size_t)s1 * 1024 + threadIdx.x * 4) = bv;
  *(bf16x4*)(Xg + (size_t)s2 * 1024 + threadIdx.x * 4) = bv;
}

// ---------------- transpose + fp32->bf16: in [E][R][C] -> out [E][C][R] ----
__global__ __launch_bounds__(256) void tconv_kernel(
    const float* __restrict__ in, bf16* __restrict__ out, int R, int C) {
  __shared__ float tile[64][65];
  size_t base = (size_t)blockIdx.z * R * C;
  int gr0 = blockIdx.y * 64, gc0 = blockIdx.x * 64;
#pragma unroll
  for (int i = 0; i < 16; i++) {
    int idx = threadIdx.x + i * 256;
    int r = idx >> 6, c = idx & 63;
    tile[r][c] = in[base + (size_t)(gr0 + r) * C + gc0 + c];
  }
  __syncthreads();
  int rr0 = (threadIdx.x & 15) * 4;
#pragma unroll
  for (int i = 0; i < 4; i++) {
    int cc = (threadIdx.x >> 4) + i * 16;
    bf16x4 v = { (bf16)tile[rr0][cc], (bf16)tile[rr0 + 1][cc],
                 (bf16)tile[rr0 + 2][cc], (bf16)tile[rr0 + 3][cc] };
    *(bf16x4*)&out[base + (size_t)(gc0 + cc) * R + gr0 + rr0] = v;
  }
}

// ================= 8-phase GEMM core (BM=128,BN=256,BK=64) =================
// A [M][K], B [N][K], bf16 K-contig. LDS buf (48KB): A [128 rows][128B] at 0,
// B [256 rows][128B] at 16384. 3 buffers. Row swizzle: element byte b of row r
// stored at b ^ ((r&7)<<4); global source pre-applies the same XOR so the
// linear global_load_lds write lands swizzled-correct (both-sides rule).
// Per K-tile: 2 phases (kk=0,1). Phase: 8x ds_read_b128 frags + 3x GLD16
// (tile kt+2) -> s_barrier -> lgkmcnt(0) -> setprio(1) 16 MFMA setprio(0)
// -> [vmcnt(6) at tile end] -> s_barrier.
__device__ __forceinline__ void gemm8_mainloop(
    const bf16* __restrict__ Abase, const bf16* __restrict__ Bbase,
    int K, char* smem, f32x4 acc[4][4], int wr, int wc, int l) {
  const int NT = K >> 6;
  int tid = threadIdx.x;
  size_t K2 = (size_t)K * 2;  // row stride in bytes
  // staging source pointers (slot = tid*16 + j*8192 within region)
  const char* sA0; const char* sA1;
  const char* sB0; const char* sB1; const char* sB2; const char* sB3;
  {
    int p0 = tid * 16, r0 = p0 >> 7, c0 = p0 & 127;
    int p1 = p0 + 8192, r1 = p1 >> 7, c1 = p1 & 127;
    int p2 = p0 + 16384, r2 = p2 >> 7, c2 = p2 & 127;
    int p3 = p0 + 24576, r3 = p3 >> 7, c3 = p3 & 127;
    sA0 = (const char*)Abase + (size_t)r0 * K2 + (c0 ^ ((r0 & 7) << 4));
    sA1 = (const char*)Abase + (size_t)r1 * K2 + (c1 ^ ((r1 & 7) << 4));
    sB0 = (const char*)Bbase + (size_t)r0 * K2 + (c0 ^ ((r0 & 7) << 4));
    sB1 = (const char*)Bbase + (size_t)r1 * K2 + (c1 ^ ((r1 & 7) << 4));
    sB2 = (const char*)Bbase + (size_t)r2 * K2 + (c2 ^ ((r2 & 7) << 4));
    sB3 = (const char*)Bbase + (size_t)r3 * K2 + (c3 ^ ((r3 & 7) << 4));
  }
  const int dA = tid * 16;           // LDS dest (bytes) within buf, A region
  const int dB = 16384 + tid * 16;   // B region
  // fragment read offsets (kk=0); kk=1 is ^64 (swizzle XOR preserves bit6 flip)
  int offA[4], offBf[4];
#pragma unroll
  for (int t = 0; t < 4; t++) {
    int ra = wr * 64 + t * 16 + (l & 15);
    offA[t] = ra * 128 + ((((l >> 4) << 4)) ^ ((ra & 7) << 4));
    int rb = wc * 64 + t * 16 + (l & 15);
    offBf[t] = 16384 + rb * 128 + ((((l >> 4) << 4)) ^ ((rb & 7) << 4));
  }
  // prologue: stage tiles 0 and 1 (12 loads in flight)
#pragma unroll
  for (int t = 0; t < 2; t++) {
    char* bu = smem + t * 49152;
    GLD16(sA0 + t * 128, bu + dA);
    GLD16(sA1 + t * 128, bu + dA + 8192);
    GLD16(sB0 + t * 128, bu + dB);
    GLD16(sB1 + t * 128, bu + dB + 8192);
    GLD16(sB2 + t * 128, bu + dB + 16384);
    GLD16(sB3 + t * 128, bu + dB + 24576);
  }
  sA0 += 256; sA1 += 256; sB0 += 256; sB1 += 256; sB2 += 256; sB3 += 256;
  asm volatile("s_waitcnt vmcnt(6)" ::: "memory");  // tile 0 resident
  __builtin_amdgcn_s_barrier();
  char* bc = smem;                // compute buffer (tile kt)
  char* bn2 = smem + 2 * 49152;  // stage target (tile kt+2)
  for (int kt = 0; kt < NT; kt++) {
    bool st = (kt + 2) < NT;
    bf16x8 af[4], bfv[4];
    // ---- phase 0 (kk=0) ----
#pragma unroll
    for (int t = 0; t < 4; t++) {
      af[t] = *(const bf16x8*)(bc + offA[t]);
      bfv[t] = *(const bf16x8*)(bc + offBf[t]);
    }
    if (st) {
      GLD16(sA0, bn2 + dA);
      GLD16(sA1, bn2 + dA + 8192);
      GLD16(sB0, bn2 + dB);
    }
    __builtin_amdgcn_s_barrier();
    asm volatile("s_waitcnt lgkmcnt(0)" ::: "memory");
    __builtin_amdgcn_s_setprio(1);
#pragma unroll
    for (int mf = 0; mf < 4; mf++)
#pragma unroll
      for (int nf = 0; nf < 4; nf++)
        acc[mf][nf] = __builtin_amdgcn_mfma_f32_16x16x32_bf16(bfv[nf], af[mf], acc[mf][nf], 0, 0, 0);
    __builtin_amdgcn_s_setprio(0);
    __builtin_amdgcn_s_barrier();
    // ---- phase 1 (kk=1) ----
#pragma unroll
    for (int t = 0; t < 4; t++) {
      af[t] = *(const bf16x8*)(bc + (offA[t] ^ 64));
      bfv[t] = *(const bf16x8*)(bc + (offBf[t] ^ 64));
    }
    if (st) {
      GLD16(sB1, bn2 + dB + 8192);
      GLD16(sB2, bn2 + dB + 16384);
      GLD16(sB3, bn2 + dB + 24576);
      sA0 += 128; sA1 += 128; sB0 += 128; sB1 += 128; sB2 += 128; sB3 += 128;
    }
    __builtin_amdgcn_s_barrier();
    asm volatile("s_waitcnt lgkmcnt(0)" ::: "memory");
    __builtin_amdgcn_s_setprio(1);
#pragma unroll
    for (int mf = 0; mf < 4; mf++)
#pragma unroll
      for (int nf = 0; nf < 4; nf++)
        acc[mf][nf] = __builtin_amdgcn_mfma_f32_16x16x32_bf16(bfv[nf], af[mf], acc[mf][nf], 0, 0, 0);
    __builtin_amdgcn_s_setprio(0);
    if (st) {
      asm volatile("s_waitcnt vmcnt(6)" ::: "memory");   // tile kt+1 resident
    } else if (kt + 1 < NT) {
      asm volatile("s_waitcnt vmcnt(0)" ::: "memory");   // drain for last tile
    }
    __builtin_amdgcn_s_barrier();
    bc += 49152; if (bc == smem + 147456) bc = smem;
    bn2 += 49152; if (bn2 == smem + 147456) bn2 = smem;
  }
}

// ---------------- grouped GEMM1: h = gelu(Xg @ W1[e] + b1[e]) ----------------
// Grid 2176: xcd=b&7, j=b>>3 (0..271); m_tile=xcd*17+(j>>4), n_tile=j&15.
__global__ __launch_bounds__(512) void gemm1_kernel(
    const bf16* __restrict__ Xg, const bf16* __restrict__ W1t,
    const float* __restrict__ b1, bf16* __restrict__ hbuf,
    const int* __restrict__ off) {
  __shared__ __align__(16) char smem[147456];
  int b = blockIdx.x;
  int xcd = b & 7, j = b >> 3;
  int m_tile = xcd * 17 + (j >> 4);
  int n_tile = j & 15;
  int row0 = m_tile * 128;
  if (row0 >= off[8]) return;
  int e = 0;
#pragma unroll
  for (int i = 0; i < 8; i++) { if (row0 >= off[i + 1]) e = i + 1; }
  int tid = threadIdx.x;
  int w = tid >> 6, l = tid & 63;
  int wr = w >> 2, wc = w & 3;
  f32x4 acc[4][4];
#pragma unroll
  for (int a = 0; a < 4; a++)
#pragma unroll
    for (int bb = 0; bb < 4; bb++) acc[a][bb] = (f32x4){0.f, 0.f, 0.f, 0.f};
  gemm8_mainloop(Xg + (size_t)row0 * 1024,
                 W1t + ((size_t)e * 4096 + n_tile * 256) * 1024,
                 1024, smem, acc, wr, wc, l);
  int mrow = l & 15, nq = (l >> 4) * 4;
  int gn0 = n_tile * 256 + wc * 64 + nq;
  f32x4 bv[4];
#pragma unroll
  for (int nf = 0; nf < 4; nf++)
    bv[nf] = *(const f32x4*)(b1 + e * 4096 + gn0 + nf * 16);
#pragma unroll
  for (int mf = 0; mf < 4; mf++) {
    int gm = row0 + wr * 64 + mf * 16 + mrow;
    bf16* rp = hbuf + (size_t)gm * 4096 + gn0;
#pragma unroll
    for (int nf = 0; nf < 4; nf++) {
      bf16x4 o;
#pragma unroll
      for (int jj = 0; jj < 4; jj++)
        o[jj] = (bf16)gelu_fast(acc[mf][nf][jj] + bv[nf][jj]);
      *(bf16x4*)(rp + nf * 16) = o;
    }
  }
}

// ---------------- grouped GEMM2: y[slot] = h @ W2[e] + b2[e] (bf16) ---------
// Grid 544: xcd=b&7, j=b>>3 (0..67); m_tile=xcd*17+(j>>2), n_tile=j&3.
__global__ __launch_bounds__(512) void gemm2_kernel(
    const bf16* __restrict__ hbuf, const bf16* __restrict__ W2t,
    const float* __restrict__ b2, bf16* __restrict__ yb,
    const int* __restrict__ off) {
  __shared__ __align__(16) char smem[147456];
  int b = blockIdx.x;
  int xcd = b & 7, j = b >> 3;
  int m_tile = xcd * 17 + (j >> 2);
  int n_tile = j & 3;
  int row0 = m_tile * 128;
  if (row0 >= off[8]) return;
  int e = 0;
#pragma unroll
  for (int i = 0; i < 8; i++) { if (row0 >= off[i + 1]) e = i + 1; }
  int tid = threadIdx.x;
  int w = tid >> 6, l = tid & 63;
  int wr = w >> 2, wc = w & 3;
  f32x4 acc[4][4];
#pragma unroll
  for (int a = 0; a < 4; a++)
#pragma unroll
    for (int bb = 0; bb < 4; bb++) acc[a][bb] = (f32x4){0.f, 0.f, 0.f, 0.f};
  gemm8_mainloop(hbuf + (size_t)row0 * 4096,
                 W2t + ((size_t)e * 1024 + n_tile * 256) * 4096,
                 4096, smem, acc, wr, wc, l);
  int mrow = l & 15, nq = (l >> 4) * 4;
  int gn0 = n_tile * 256 + wc * 64 + nq;
  f32x4 bv[4];
#pragma unroll
  for (int nf = 0; nf < 4; nf++)
    bv[nf] = *(const f32x4*)(b2 + e * 1024 + gn0 + nf * 16);
#pragma unroll
  for (int mf = 0; mf < 4; mf++) {
    int gm = row0 + wr * 64 + mf * 16 + mrow;
    bf16* rp = yb + (size_t)gm * 1024 + gn0;
#pragma unroll
    for (int nf = 0; nf < 4; nf++) {
      bf16x4 o;
#pragma unroll
      for (int jj = 0; jj < 4; jj++)
        o[jj] = (bf16)(acc[mf][nf][jj] + bv[nf][jj]);
      *(bf16x4*)(rp + nf * 16) = o;
    }
  }
}

// ---------------- combine: out[t] = p0[t] * (y[s1] + y[s2]) -----------------
__global__ __launch_bounds__(256) void combine_kernel(
    const bf16* __restrict__ yb, const int* __restrict__ slot1,
    const int* __restrict__ slot2, const float* __restrict__ p0arr,
    float* __restrict__ out) {
  int t = blockIdx.x;
  int s1 = slot1[t], s2 = slot2[t];
  float w0 = p0arr[t];
  bf16x4 a = *(const bf16x4*)(yb + (size_t)s1 * 1024 + threadIdx.x * 4);
  bf16x4 b = *(const bf16x4*)(yb + (size_t)s2 * 1024 + threadIdx.x * 4);
  float4 o;
  o.x = w0 * ((float)a[0] + (float)b[0]);
  o.y = w0 * ((float)a[1] + (float)b[1]);
  o.z = w0 * ((float)a[2] + (float)b[2]);
  o.w = w0 * ((float)a[3] + (float)b[3]);
  *(float4*)(out + (size_t)t * 1024 + threadIdx.x * 4) = o;
}

extern "C" void kernel_launch(void* const* d_in, const int* in_sizes, int n_in,
                              void* d_out, int out_size, void* d_ws, size_t ws_size,
                              hipStream_t stream) {
  const float* x  = (const float*)d_in[0];
  const float* Wr = (const float*)d_in[1];
  const float* br = (const float*)d_in[2];
  const float* W1 = (const float*)d_in[3];
  const float* b1 = (const float*)d_in[4];
  const float* W2 = (const float*)d_in[5];
  const float* b2 = (const float*)d_in[6];
  float* out = (float*)d_out;

  char* ws = (char*)d_ws;
  int*   off   = (int*)(ws + 0);
  int*   e01   = (int*)(ws + 256);
  float* p0    = (float*)(ws + 33024);
  int*   slot1 = (int*)(ws + 65792);
  int*   slot2 = (int*)(ws + 98560);
  bf16*  Xg    = (bf16*)(ws + 131584);          // reused as ybuf after gemm1
  bf16*  W1t   = (bf16*)(ws + 35783168ULL);
  bf16*  W2t   = (bf16*)(ws + 102892032ULL);
  bf16*  hb    = (bf16*)(ws + 170000896ULL);
  bf16*  yb    = Xg;

  tconv_kernel<<<dim3(64, 16, 8), 256, 0, stream>>>(W1, W1t, 1024, 4096);
  tconv_kernel<<<dim3(16, 64, 8), 256, 0, stream>>>(W2, W2t, 4096, 1024);
  router_kernel<<<2048, 256, 0, stream>>>(x, Wr, br, e01, p0);
  slots_kernel<<<1, 1024, 0, stream>>>(e01, off, slot1, slot2);
  gather_kernel<<<8192, 256, 0, stream>>>(x, slot1, slot2, Xg);
  gemm1_kernel<<<2176, 512, 0, stream>>>(Xg, W1t, b1, hb, off);
  gemm2_kernel<<<544, 512, 0, stream>>>(hb, W2t, b2, yb, off);
  combine_kernel<<<8192, 256, 0, stream>>>(yb, slot1, slot2, p0, out);
}